// Round 3
// baseline (6008.795 us; speedup 1.0000x reference)
//
#include <hip/hip_runtime.h>
#include <math.h>

// ---------------------------------------------------------------------------
// VQVAEZMultiScale round 3 — bf16-split MFMA bulk match + fp64 rescue.
//   v_k = 2<e,c_k> - ||c_k||^2 determines argmin-d and prob (||e||^2 cancels).
//   Bulk: e,c split into bf16 hi/lo; 3 MFMA passes (hh + hl + lh); worst-case
//   dot error ~2e-4. Rows with top2 v-gap < EPS_V=0.01 and pixels with prob
//   gap < EPS_P=0.02 are recomputed exactly in fp64 (round-2-proven numerics).
// Workspace layout (float units), total ~57.7 MB:
//   feat   [43008][256] f32        @ 0
//   partials [75776][8] float4     @ 11010048   (v1,v2,k1bits,S per 64-code slice)
//   prob   f32[43008]              @ 13434880
//   idx1   int[43008]              @ 13477888
//   idx2   int[32768]              @ 13520896
//   cnf    f32[1024]               @ 13553664
//   cnd    double[1024]            @ 13554688
//   cbs    bf16[2][2][512][256]    @ 13556736   (book, split, code, ch)
//   img1   [8][3][128][128]        @ 13818880
//   img2   [8][3][64][64]          @ 14212096
//   rlist  int[75776]              @ 14310400
//   dlist  int[32768]              @ 14386176
//   cnt    int[2]                  @ 14418944
// Output: out0 @0, zidx @8388608 (as float), ste0 @8454144 (all f32, NCHW)
// ---------------------------------------------------------------------------

#define FEAT_OFF   0
#define PART_OFF   11010048
#define PROB_OFF   13434880
#define IDX1_OFF   13477888
#define IDX2_OFF   13520896
#define CNF_OFF    13553664
#define CND_OFF    13554688
#define CBS_OFF    13556736
#define IMG1_OFF   13818880
#define IMG2_OFF   14212096
#define RLIST_OFF  14310400
#define DLIST_OFF  14386176
#define CNT_OFF    14418944

#define EPS_V 0.01f
#define EPS_P 0.02f

typedef __attribute__((ext_vector_type(8))) short short8;
typedef __attribute__((ext_vector_type(4))) float f32x4;

__device__ inline unsigned short f2bf(float x) {
    unsigned u = __float_as_uint(x);
    return (unsigned short)((u + 0x7FFFu + ((u >> 16) & 1u)) >> 16);
}
__device__ inline float bf2f(unsigned short h) {
    return __uint_as_float(((unsigned)h) << 16);
}

__global__ void zero_cnt(int* cnt) { if (threadIdx.x < 2) cnt[threadIdx.x] = 0; }

// ---- bilinear downsample (reference order: H-average first, then W)
__global__ void ds_kernel(const float* __restrict__ img, float* __restrict__ out,
                          int Hout, int Wout, int o, int f) {
    int i = blockIdx.x * blockDim.x + threadIdx.x;
    if (i >= 8 * 3 * Hout * Wout) return;
    int x = i % Wout;
    int t = i / Wout;
    int y = t % Hout;
    int bc = t / Hout;
    const float* base = img + ((size_t)bc * 256 + (size_t)(y * f + o)) * 256;
    int cx = x * f + o;
    float v00 = base[cx],     v10 = base[256 + cx];
    float v01 = base[cx + 1], v11 = base[256 + cx + 1];
    out[i] = ((v00 + v10) * 0.5f + (v01 + v11) * 0.5f) * 0.5f;
}

// ---- per-code squared norms, fp64 + f32 copies
__global__ void cnorm_kernel(const float* __restrict__ cb, double* __restrict__ cnd,
                             float* __restrict__ cnf) {
    int row = blockIdx.x;                    // 0..1023
    const float* p = cb + (size_t)row * 256;
    int lane = threadIdx.x;                  // 64
    double s = 0.0;
    for (int c = lane; c < 256; c += 64) {
        double v = (double)p[c];
        s = fma(v, v, s);
    }
    #pragma unroll
    for (int off = 32; off; off >>= 1) s += __shfl_down(s, off);
    if (lane == 0) { cnd[row] = s; cnf[row] = (float)s; }
}

// ---- split both codebooks into bf16 hi/lo planes
__global__ void split_cb(const float* __restrict__ codebooks, unsigned short* __restrict__ cbs) {
    int i = blockIdx.x * 256 + threadIdx.x;      // over 2*512*256 = 262144
    if (i >= 262144) return;
    int book = i >> 17, rem = i & 131071;        // rem = code*256 + ch
    float c = codebooks[(size_t)book * 131072 + rem];
    unsigned short h0 = f2bf(c);
    unsigned short h1 = f2bf(c - bf2f(h0));
    size_t base = (size_t)book * 262144;
    cbs[base + rem] = h0;                        // split 0 plane
    cbs[base + 131072 + rem] = h1;               // split 1 plane
}

// ---- stride-4 patchify conv, all 3 scales in one launch (identical math to r2)
__launch_bounds__(256)
__global__ void encode_all(const float* __restrict__ image,
                           const float* __restrict__ img1,
                           const float* __restrict__ img2,
                           const float* __restrict__ w,
                           const float* __restrict__ bias,
                           float* __restrict__ feat) {
    __shared__ float patch[12 * 256];
    int bid = blockIdx.x;
    const float* img; int Hout, rowbase, local;
    if (bid < 512)      { img = image; Hout = 64; rowbase = 0;     local = bid; }
    else if (bid < 768) { img = img1;  Hout = 32; rowbase = 32768; local = bid - 512; }
    else                { img = img2;  Hout = 16; rowbase = 40960; local = bid - 768; }
    int Wout = Hout;
    int tid = threadIdx.x;
    int b = local / Hout, y = local % Hout;
    int Himg = Hout * 4, Wimg = Wout * 4;

    const float* ibase = img + (size_t)b * 3 * Himg * Wimg;
    int nload = 12 * Wimg;
    for (int i = tid; i < nload; i += 256) {
        int col = i % Wimg, r = i / Wimg;    // r = ci*4 + kh
        int ci = r >> 2, kh = r & 3;
        patch[r * Wimg + col] = ibase[((size_t)ci * Himg + 4 * y + kh) * Wimg + col];
    }
    float wr[48];
    #pragma unroll
    for (int j = 0; j < 48; j++) wr[j] = w[tid * 48 + j];
    float bv = bias[tid];
    __syncthreads();

    int rb = rowbase + (b * Hout + y) * Wout;
    for (int x = 0; x < Wout; x++) {
        float acc = 0.f;
        #pragma unroll
        for (int ci = 0; ci < 3; ci++)
            #pragma unroll
            for (int kh = 0; kh < 4; kh++) {
                const float* pr = &patch[(ci * 4 + kh) * Wimg + 4 * x];
                #pragma unroll
                for (int kw = 0; kw < 4; kw++)
                    acc = fmaf(pr[kw], wr[ci * 16 + kh * 4 + kw], acc);
            }
        feat[(size_t)(rb + x) * 256 + tid] = acc + bv;
    }
}

// ---- bulk MFMA match. Block: 128 virtual-rows x 128 codes; grid 592x4.
//      Virtual rows: [0,43008) = feat rows vs book0; [43008,75776) = feat rows
//      0..32767 vs book1. 3 bf16 passes: e0*c0 + e0*c1 + e1*c0.
//      Per row, per 64-code slice: write (v1, v2, k1, S) partial.
__launch_bounds__(256, 3)
__global__ void match_bulk(const float* __restrict__ feat,
                           const unsigned short* __restrict__ cbs,
                           const float* __restrict__ cnf,
                           float* __restrict__ partials) {
    __shared__ unsigned short A0[128][40], A1[128][40], B0s[128][40], B1s[128][40];
    int bid = blockIdx.x;
    int codeblk = bid & 3, rowtile = bid >> 2;     // 4 x 592
    int book = (rowtile >= 336) ? 1 : 0;
    int frow0 = book ? (rowtile - 336) * 128 : rowtile * 128;
    int vr0 = rowtile * 128;
    int tid = threadIdx.x;
    int wid = tid >> 6, l = tid & 63;
    int waveY = wid & 1, waveX = wid >> 1;
    int lm = l & 15, lq = l >> 4, kq = lq * 8;

    f32x4 acc[4][4];
    #pragma unroll
    for (int rt = 0; rt < 4; rt++)
        #pragma unroll
        for (int ct = 0; ct < 4; ct++) acc[rt][ct] = (f32x4)0.0f;

    const float4* feat4 = (const float4*)feat;
    const unsigned short* cbbase = cbs + (size_t)book * 262144;

    for (int kc = 0; kc < 8; kc++) {
        // stage A: 128 rows x 32 ch fp32 -> split to bf16 hi/lo
        #pragma unroll
        for (int i = 0; i < 4; i++) {
            int f4 = i * 256 + tid;
            int row = f4 >> 3, c4 = f4 & 7;
            float4 v = feat4[(size_t)(frow0 + row) * 64 + kc * 8 + c4];
            ushort4 h0, h1;
            h0.x = f2bf(v.x); h1.x = f2bf(v.x - bf2f(h0.x));
            h0.y = f2bf(v.y); h1.y = f2bf(v.y - bf2f(h0.y));
            h0.z = f2bf(v.z); h1.z = f2bf(v.z - bf2f(h0.z));
            h0.w = f2bf(v.w); h1.w = f2bf(v.w - bf2f(h0.w));
            *(ushort4*)&A0[row][c4 * 4] = h0;
            *(ushort4*)&A1[row][c4 * 4] = h1;
        }
        // stage B: 128 codes x 32 ch, both pre-split planes
        #pragma unroll
        for (int i = 0; i < 4; i++) {
            int lid = i * 256 + tid;
            int split = lid >> 9, rem = lid & 511;
            int code = rem >> 2, c8 = (rem & 3) * 8;
            uint4 raw = *(const uint4*)(cbbase + ((size_t)split * 512 + codeblk * 128 + code) * 256
                                        + kc * 32 + c8);
            if (split) *(uint4*)&B1s[code][c8] = raw;
            else       *(uint4*)&B0s[code][c8] = raw;
        }
        __syncthreads();
        short8 a0[4], a1[4], b0[4], b1[4];
        #pragma unroll
        for (int t = 0; t < 4; t++) {
            a0[t] = *(const short8*)&A0[waveY * 64 + t * 16 + lm][kq];
            a1[t] = *(const short8*)&A1[waveY * 64 + t * 16 + lm][kq];
            b0[t] = *(const short8*)&B0s[waveX * 64 + t * 16 + lm][kq];
            b1[t] = *(const short8*)&B1s[waveX * 64 + t * 16 + lm][kq];
        }
        #pragma unroll
        for (int rt = 0; rt < 4; rt++)
            #pragma unroll
            for (int ct = 0; ct < 4; ct++) {
                acc[rt][ct] = __builtin_amdgcn_mfma_f32_16x16x32_bf16(a0[rt], b0[ct], acc[rt][ct], 0, 0, 0);
                acc[rt][ct] = __builtin_amdgcn_mfma_f32_16x16x32_bf16(a0[rt], b1[ct], acc[rt][ct], 0, 0, 0);
                acc[rt][ct] = __builtin_amdgcn_mfma_f32_16x16x32_bf16(a1[rt], b0[ct], acc[rt][ct], 0, 0, 0);
            }
        __syncthreads();
    }

    // epilogue: v = 2*dot - cn; per row top2+argmax+sumexp over this wave's 64 codes
    float cnv[4];
    #pragma unroll
    for (int ct = 0; ct < 4; ct++)
        cnv[ct] = cnf[book * 512 + codeblk * 128 + waveX * 64 + ct * 16 + lm];
    float4* part4 = (float4*)partials;

    #pragma unroll
    for (int rt = 0; rt < 4; rt++) {
        #pragma unroll
        for (int j = 0; j < 4; j++) {
            float v[4];
            #pragma unroll
            for (int ct = 0; ct < 4; ct++)
                v[ct] = 2.0f * acc[rt][ct][j] - cnv[ct];
            // local top2 (codes ascend with ct for fixed lane)
            float m1 = v[0], m2 = -3.4e38f;
            int k1 = codeblk * 128 + waveX * 64 + 0 * 16 + lm;
            #pragma unroll
            for (int ct = 1; ct < 4; ct++) {
                int kk = codeblk * 128 + waveX * 64 + ct * 16 + lm;
                if (v[ct] > m1 || (v[ct] == m1 && kk < k1)) { m2 = m1; m1 = v[ct]; k1 = kk; }
                else m2 = fmaxf(m2, v[ct]);
            }
            // butterfly across the 16-lane code group
            #pragma unroll
            for (int off = 1; off < 16; off <<= 1) {
                float mo1 = __shfl_xor(m1, off);
                float mo2 = __shfl_xor(m2, off);
                int ko1 = __shfl_xor(k1, off);
                if (mo1 > m1 || (mo1 == m1 && ko1 < k1)) { m2 = fmaxf(m1, mo2); m1 = mo1; k1 = ko1; }
                else m2 = fmaxf(m2, mo1);
            }
            // sum exp(v - m1)
            float s = 0.f;
            #pragma unroll
            for (int ct = 0; ct < 4; ct++) s += expf(v[ct] - m1);
            #pragma unroll
            for (int off = 1; off < 16; off <<= 1) s += __shfl_xor(s, off);
            if (lm == 0) {
                int vr = vr0 + waveY * 64 + rt * 16 + lq * 4 + j;
                float4 st = make_float4(m1, m2, __int_as_float(k1), s);
                part4[(size_t)vr * 8 + codeblk * 2 + waveX] = st;
            }
        }
    }
}

// ---- combine the 8 per-slice partials of each row; write idx/prob; flag rescues
__global__ void combine_rows(const float* __restrict__ partials,
                             int* __restrict__ idx1, int* __restrict__ idx2,
                             float* __restrict__ prob,
                             int* __restrict__ rlist, int* __restrict__ cnt) {
    int vr = blockIdx.x * 256 + threadIdx.x;      // grid 296*256 = 75776 exact
    const float4* p = (const float4*)partials + (size_t)vr * 8;
    float sm[8], ss[8];
    float4 a = p[0];
    float m1 = a.x, m2 = a.y; int k1 = __float_as_int(a.z);
    sm[0] = a.x; ss[0] = a.w;
    #pragma unroll
    for (int j = 1; j < 8; j++) {
        float4 b = p[j];
        sm[j] = b.x; ss[j] = b.w;
        int kk = __float_as_int(b.z);
        if (b.x > m1 || (b.x == m1 && kk < k1)) { m2 = fmaxf(m1, b.y); m1 = b.x; k1 = kk; }
        else m2 = fmaxf(m2, fmaxf(b.x, -3.4e38f));
    }
    float S = 0.f;
    #pragma unroll
    for (int j = 0; j < 8; j++) S += ss[j] * expf(sm[j] - m1);
    if (vr < 43008) { idx1[vr] = k1; prob[vr] = 1.0f / S; }
    else idx2[vr - 43008] = k1;
    if (m1 - m2 < EPS_V) { int pos = atomicAdd(cnt, 1); rlist[pos] = vr; }
}

// ---- exact fp64 recompute for flagged rows (idx + prob)
__launch_bounds__(256)
__global__ void rescue_exact(const float* __restrict__ feat,
                             const float* __restrict__ codebooks,
                             const double* __restrict__ cnd,
                             const int* __restrict__ rlist, const int* __restrict__ cnt,
                             int* __restrict__ idx1, int* __restrict__ idx2,
                             float* __restrict__ prob) {
    __shared__ double sfd[256];
    __shared__ double rv[4]; __shared__ int rk[4]; __shared__ double rs[4];
    __shared__ double gvmax; __shared__ int gkmax;
    int tid = threadIdx.x;
    int lane = tid & 63, wave = tid >> 6;
    int n = cnt[0];
    for (int e = blockIdx.x; e < n; e += gridDim.x) {
        int vr = rlist[e];
        int book = vr >= 43008;
        int fr = book ? vr - 43008 : vr;
        sfd[tid] = (double)feat[(size_t)fr * 256 + tid];
        __syncthreads();
        const float* cb = codebooks + (size_t)book * 131072;
        double vloc[2]; int kk[2];
        #pragma unroll
        for (int h = 0; h < 2; h++) {
            int k = h * 256 + tid;
            const float* cp = cb + (size_t)k * 256;
            double dot = 0.0;
            for (int c = 0; c < 256; c++) dot = fma((double)cp[c], sfd[c], dot);
            vloc[h] = 2.0 * dot - cnd[book * 512 + k];
            kk[h] = k;
        }
        double bv = vloc[0]; int bk = kk[0];
        if (vloc[1] > bv || (vloc[1] == bv && kk[1] < bk)) { bv = vloc[1]; bk = kk[1]; }
        #pragma unroll
        for (int off = 32; off; off >>= 1) {
            double vo = __shfl_xor(bv, off);
            int ko = __shfl_xor(bk, off);
            if (vo > bv || (vo == bv && ko < bk)) { bv = vo; bk = ko; }
        }
        if (lane == 0) { rv[wave] = bv; rk[wave] = bk; }
        __syncthreads();
        if (tid == 0) {
            double v0 = rv[0]; int K = rk[0];
            #pragma unroll
            for (int w = 1; w < 4; w++)
                if (rv[w] > v0 || (rv[w] == v0 && rk[w] < K)) { v0 = rv[w]; K = rk[w]; }
            gvmax = v0; gkmax = K;
        }
        __syncthreads();
        double vm = gvmax;
        double s = exp(vloc[0] - vm) + exp(vloc[1] - vm);
        #pragma unroll
        for (int off = 32; off; off >>= 1) s += __shfl_xor(s, off);
        if (lane == 0) rs[wave] = s;
        __syncthreads();
        if (tid == 0) {
            double S = ((rs[0] + rs[1]) + rs[2]) + rs[3];
            if (book) idx2[fr] = gkmax;
            else { idx1[vr] = gkmax; prob[vr] = (float)(1.0 / S); }
        }
        __syncthreads();
    }
}

// ---- fuse stage 1: decide per pixel; defer prob-fragile pixels to fuse2
__launch_bounds__(256)
__global__ void fuse1(const float* __restrict__ feat,
                      const float* __restrict__ prob,
                      const int* __restrict__ idx1, const int* __restrict__ idx2,
                      const float* __restrict__ codebooks,
                      float* __restrict__ out0, float* __restrict__ outZ,
                      float* __restrict__ outS,
                      int* __restrict__ dlist, int* __restrict__ cnt) {
    __shared__ int rsel_s[64], i1_s[64], i2_s[64], defer_s[64];
    int tid = threadIdx.x;
    int b = blockIdx.x >> 6, y = blockIdx.x & 63;

    if (tid < 64) {
        int x = tid;
        int r0 = (b * 64 + y) * 64 + x;
        int r1 = 32768 + (b * 32 + (y >> 1)) * 32 + (x >> 1);
        int r2 = 40960 + (b * 16 + (y >> 2)) * 16 + (x >> 2);
        float p0 = prob[r0], p1 = prob[r1], p2 = prob[r2];
        int rsel = r0; float best = p0;          // strict > keeps first-max
        if (p1 > best) { best = p1; rsel = r1; }
        if (p2 > best) { best = p2; rsel = r2; }
        float second = -1.f;
        if (rsel != r0) second = fmaxf(second, p0);
        if (rsel != r1) second = fmaxf(second, p1); else second = fmaxf(second, p0);
        // (careful: compute second as max of the two non-selected)
        second = (rsel == r0) ? fmaxf(p1, p2) : (rsel == r1) ? fmaxf(p0, p2) : fmaxf(p0, p1);
        int defer = (best - second < EPS_P) ? 1 : 0;
        defer_s[x] = defer;
        if (defer) {
            int pos = atomicAdd(cnt + 1, 1);
            dlist[pos] = (b << 12) | (y << 6) | x;
            rsel_s[x] = r0; i1_s[x] = 0; i2_s[x] = 0;   // unused
        } else {
            int i1 = idx1[rsel], i2 = idx2[r0];
            rsel_s[x] = rsel; i1_s[x] = i1; i2_s[x] = i2;
            size_t zb = (size_t)b * 8192 + (size_t)y * 64 + x;
            outZ[zb] = (float)i1;
            outZ[zb + 4096] = (float)i2;
        }
    }
    __syncthreads();

    int x = tid & 63, cc = tid >> 6;
    int r0 = (b * 64 + y) * 64 + x;
    const float* e0p = feat + (size_t)r0 * 256;
    const float* e1p = feat + (size_t)rsel_s[x] * 256;
    const float* q1p = codebooks + (size_t)i1_s[x] * 256;
    const float* q2p = codebooks + (size_t)(512 + i2_s[x]) * 256;
    int defer = defer_s[x];
    for (int it = 0; it < 64; it++) {
        int c = it * 4 + cc;
        float e0 = e0p[c];
        size_t o = (((size_t)b * 256 + c) * 64 + y) * 64 + x;
        out0[o] = e0;                              // out0 never depends on decisions
        if (!defer) {
            float e1 = e1p[c], q1 = q1p[c], q2 = q2p[c];
            float ef = (e1 + e0) * 0.5f;
            float qf = (q1 + q2) * 0.5f;
            outS[o] = ef + (qf - ef);
        }
    }
}

// ---- fuse stage 2: deferred pixels, full fp64 (3 rows x 512 codes each)
__launch_bounds__(256)
__global__ void fuse2(const float* __restrict__ feat,
                      const float* __restrict__ codebooks,
                      const double* __restrict__ cnd,
                      const int* __restrict__ idx2,
                      const int* __restrict__ dlist, const int* __restrict__ cnt,
                      float* __restrict__ outZ, float* __restrict__ outS) {
    __shared__ double sfd[256];
    __shared__ double rv[4]; __shared__ int rk[4]; __shared__ double rs[4];
    __shared__ double gvmax;
    __shared__ double pRes[3]; __shared__ int kRes[3];
    __shared__ int selS, i2S;
    int tid = threadIdx.x;
    int lane = tid & 63, wave = tid >> 6;
    int n = cnt[1];
    for (int e = blockIdx.x; e < n; e += gridDim.x) {
        int px = dlist[e];
        int b = px >> 12, y = (px >> 6) & 63, x = px & 63;
        int r0 = (b * 64 + y) * 64 + x;
        int r1 = 32768 + (b * 32 + (y >> 1)) * 32 + (x >> 1);
        int r2 = 40960 + (b * 16 + (y >> 2)) * 16 + (x >> 2);
        int rows[3] = {r0, r1, r2};
        for (int s3 = 0; s3 < 3; s3++) {
            sfd[tid] = (double)feat[(size_t)rows[s3] * 256 + tid];
            __syncthreads();
            double vloc[2];
            #pragma unroll
            for (int h = 0; h < 2; h++) {
                int k = h * 256 + tid;
                const float* cp = codebooks + (size_t)k * 256;
                double dot = 0.0;
                for (int c = 0; c < 256; c++) dot = fma((double)cp[c], sfd[c], dot);
                vloc[h] = 2.0 * dot - cnd[k];
            }
            double bv = vloc[0]; int bk = tid;
            if (vloc[1] > bv || (vloc[1] == bv && (tid + 256) < bk)) { bv = vloc[1]; bk = tid + 256; }
            #pragma unroll
            for (int off = 32; off; off >>= 1) {
                double vo = __shfl_xor(bv, off);
                int ko = __shfl_xor(bk, off);
                if (vo > bv || (vo == bv && ko < bk)) { bv = vo; bk = ko; }
            }
            if (lane == 0) { rv[wave] = bv; rk[wave] = bk; }
            __syncthreads();
            if (tid == 0) {
                double v0 = rv[0]; int K = rk[0];
                #pragma unroll
                for (int w = 1; w < 4; w++)
                    if (rv[w] > v0 || (rv[w] == v0 && rk[w] < K)) { v0 = rv[w]; K = rk[w]; }
                gvmax = v0; kRes[s3] = K;
            }
            __syncthreads();
            double vm = gvmax;
            double s = exp(vloc[0] - vm) + exp(vloc[1] - vm);
            #pragma unroll
            for (int off = 32; off; off >>= 1) s += __shfl_xor(s, off);
            if (lane == 0) rs[wave] = s;
            __syncthreads();
            if (tid == 0) pRes[s3] = 1.0 / (((rs[0] + rs[1]) + rs[2]) + rs[3]);
            __syncthreads();
        }
        if (tid == 0) {
            int sel = 0; double best = pRes[0];
            if (pRes[1] > best) { best = pRes[1]; sel = 1; }
            if (pRes[2] > best) { best = pRes[2]; sel = 2; }
            selS = sel;
            int i2 = idx2[r0];
            i2S = i2;
            size_t zb = (size_t)b * 8192 + (size_t)y * 64 + x;
            outZ[zb] = (float)kRes[sel];
            outZ[zb + 4096] = (float)i2;
        }
        __syncthreads();
        int sel = selS;
        int c = tid;
        float e0 = feat[(size_t)r0 * 256 + c];
        float e1 = feat[(size_t)rows[sel] * 256 + c];
        float q1 = codebooks[(size_t)kRes[sel] * 256 + c];
        float q2 = codebooks[(size_t)(512 + i2S) * 256 + c];
        float ef = (e1 + e0) * 0.5f;
        float qf = (q1 + q2) * 0.5f;
        size_t o = (((size_t)b * 256 + c) * 64 + y) * 64 + x;
        outS[o] = ef + (qf - ef);
        __syncthreads();
    }
}

extern "C" void kernel_launch(void* const* d_in, const int* in_sizes, int n_in,
                              void* d_out, int out_size, void* d_ws, size_t ws_size,
                              hipStream_t stream) {
    (void)in_sizes; (void)n_in; (void)out_size; (void)ws_size;
    const float* image     = (const float*)d_in[0];   // [8,3,256,256]
    const float* conv_w    = (const float*)d_in[1];   // [256,3,4,4]
    const float* conv_b    = (const float*)d_in[2];   // [256]
    const float* codebooks = (const float*)d_in[3];   // [4,512,256]

    float*  ws    = (float*)d_ws;
    float*  feat  = ws + FEAT_OFF;
    float*  parts = ws + PART_OFF;
    float*  prob  = ws + PROB_OFF;
    int*    idx1  = (int*)(ws + IDX1_OFF);
    int*    idx2  = (int*)(ws + IDX2_OFF);
    float*  cnf   = ws + CNF_OFF;
    double* cnd   = (double*)(ws + CND_OFF);
    unsigned short* cbs = (unsigned short*)(ws + CBS_OFF);
    float*  img1  = ws + IMG1_OFF;
    float*  img2  = ws + IMG2_OFF;
    int*    rlist = (int*)(ws + RLIST_OFF);
    int*    dlist = (int*)(ws + DLIST_OFF);
    int*    cnt   = (int*)(ws + CNT_OFF);

    float* out  = (float*)d_out;
    float* out0 = out;
    float* outZ = out + 8388608;
    float* outS = out + 8454144;

    zero_cnt<<<1, 64, 0, stream>>>(cnt);
    ds_kernel<<<1536, 256, 0, stream>>>(image, img1, 128, 128, 0, 2);
    ds_kernel<<<384, 256, 0, stream>>>(image, img2, 64, 64, 1, 4);
    cnorm_kernel<<<1024, 64, 0, stream>>>(codebooks, cnd, cnf);
    split_cb<<<1024, 256, 0, stream>>>(codebooks, cbs);
    encode_all<<<896, 256, 0, stream>>>(image, img1, img2, conv_w, conv_b, feat);
    match_bulk<<<2368, 256, 0, stream>>>(feat, cbs, cnf, parts);
    combine_rows<<<296, 256, 0, stream>>>(parts, idx1, idx2, prob, rlist, cnt);
    rescue_exact<<<1024, 256, 0, stream>>>(feat, codebooks, cnd, rlist, cnt, idx1, idx2, prob);
    fuse1<<<512, 256, 0, stream>>>(feat, prob, idx1, idx2, codebooks, out0, outZ, outS, dlist, cnt);
    fuse2<<<512, 256, 0, stream>>>(feat, codebooks, cnd, idx2, dlist, cnt, outZ, outS);
}

// Round 4
// 425.102 us; speedup vs baseline: 14.1349x; 14.1349x over previous
//
#include <hip/hip_runtime.h>
#include <math.h>

// ---------------------------------------------------------------------------
// VQVAEZMultiScale round 4 — bf16-split MFMA bulk match + fp64 rescue.
//   Round-3 bug: EPS_P=0.02 absolute deferred ALL pixels (probs are ~0.002-0.01,
//   cross-scale gaps ~1e-3). Fix: defer on RELATIVE prob gap (2e-3, err ~1e-4),
//   and tighten EPS_V to 1e-3 (v error <= ~3e-5). Everything else unchanged.
// Workspace layout (float units), total ~57.7 MB:
//   feat   [43008][256] f32        @ 0
//   partials [75776][8] float4     @ 11010048   (v1,v2,k1bits,S per 64-code slice)
//   prob   f32[43008]              @ 13434880
//   idx1   int[43008]              @ 13477888
//   idx2   int[32768]              @ 13520896
//   cnf    f32[1024]               @ 13553664
//   cnd    double[1024]            @ 13554688
//   cbs    bf16[2][2][512][256]    @ 13556736   (book, split, code, ch)
//   img1   [8][3][128][128]        @ 13818880
//   img2   [8][3][64][64]          @ 14212096
//   rlist  int[75776]              @ 14310400
//   dlist  int[32768]              @ 14386176
//   cnt    int[2]                  @ 14418944
// Output: out0 @0, zidx @8388608 (as float), ste0 @8454144 (all f32, NCHW)
// ---------------------------------------------------------------------------

#define FEAT_OFF   0
#define PART_OFF   11010048
#define PROB_OFF   13434880
#define IDX1_OFF   13477888
#define IDX2_OFF   13520896
#define CNF_OFF    13553664
#define CND_OFF    13554688
#define CBS_OFF    13556736
#define IMG1_OFF   13818880
#define IMG2_OFF   14212096
#define RLIST_OFF  14310400
#define DLIST_OFF  14386176
#define CNT_OFF    14418944

#define EPS_V 1e-3f          // v abs error <= ~3e-5 worst-case -> 30x margin
#define EPS_P_REL 2e-3f      // prob rel error <= ~1e-4 -> 20x margin

typedef __attribute__((ext_vector_type(8))) short short8;
typedef __attribute__((ext_vector_type(4))) float f32x4;

__device__ inline unsigned short f2bf(float x) {
    unsigned u = __float_as_uint(x);
    return (unsigned short)((u + 0x7FFFu + ((u >> 16) & 1u)) >> 16);
}
__device__ inline float bf2f(unsigned short h) {
    return __uint_as_float(((unsigned)h) << 16);
}

__global__ void zero_cnt(int* cnt) { if (threadIdx.x < 2) cnt[threadIdx.x] = 0; }

// ---- bilinear downsample (reference order: H-average first, then W)
__global__ void ds_kernel(const float* __restrict__ img, float* __restrict__ out,
                          int Hout, int Wout, int o, int f) {
    int i = blockIdx.x * blockDim.x + threadIdx.x;
    if (i >= 8 * 3 * Hout * Wout) return;
    int x = i % Wout;
    int t = i / Wout;
    int y = t % Hout;
    int bc = t / Hout;
    const float* base = img + ((size_t)bc * 256 + (size_t)(y * f + o)) * 256;
    int cx = x * f + o;
    float v00 = base[cx],     v10 = base[256 + cx];
    float v01 = base[cx + 1], v11 = base[256 + cx + 1];
    out[i] = ((v00 + v10) * 0.5f + (v01 + v11) * 0.5f) * 0.5f;
}

// ---- per-code squared norms, fp64 + f32 copies
__global__ void cnorm_kernel(const float* __restrict__ cb, double* __restrict__ cnd,
                             float* __restrict__ cnf) {
    int row = blockIdx.x;                    // 0..1023
    const float* p = cb + (size_t)row * 256;
    int lane = threadIdx.x;                  // 64
    double s = 0.0;
    for (int c = lane; c < 256; c += 64) {
        double v = (double)p[c];
        s = fma(v, v, s);
    }
    #pragma unroll
    for (int off = 32; off; off >>= 1) s += __shfl_down(s, off);
    if (lane == 0) { cnd[row] = s; cnf[row] = (float)s; }
}

// ---- split both codebooks into bf16 hi/lo planes
__global__ void split_cb(const float* __restrict__ codebooks, unsigned short* __restrict__ cbs) {
    int i = blockIdx.x * 256 + threadIdx.x;      // over 2*512*256 = 262144
    if (i >= 262144) return;
    int book = i >> 17, rem = i & 131071;        // rem = code*256 + ch
    float c = codebooks[(size_t)book * 131072 + rem];
    unsigned short h0 = f2bf(c);
    unsigned short h1 = f2bf(c - bf2f(h0));
    size_t base = (size_t)book * 262144;
    cbs[base + rem] = h0;                        // split 0 plane
    cbs[base + 131072 + rem] = h1;               // split 1 plane
}

// ---- stride-4 patchify conv, all 3 scales in one launch
__launch_bounds__(256)
__global__ void encode_all(const float* __restrict__ image,
                           const float* __restrict__ img1,
                           const float* __restrict__ img2,
                           const float* __restrict__ w,
                           const float* __restrict__ bias,
                           float* __restrict__ feat) {
    __shared__ float patch[12 * 256];
    int bid = blockIdx.x;
    const float* img; int Hout, rowbase, local;
    if (bid < 512)      { img = image; Hout = 64; rowbase = 0;     local = bid; }
    else if (bid < 768) { img = img1;  Hout = 32; rowbase = 32768; local = bid - 512; }
    else                { img = img2;  Hout = 16; rowbase = 40960; local = bid - 768; }
    int Wout = Hout;
    int tid = threadIdx.x;
    int b = local / Hout, y = local % Hout;
    int Himg = Hout * 4, Wimg = Wout * 4;

    const float* ibase = img + (size_t)b * 3 * Himg * Wimg;
    int nload = 12 * Wimg;
    for (int i = tid; i < nload; i += 256) {
        int col = i % Wimg, r = i / Wimg;    // r = ci*4 + kh
        int ci = r >> 2, kh = r & 3;
        patch[r * Wimg + col] = ibase[((size_t)ci * Himg + 4 * y + kh) * Wimg + col];
    }
    float wr[48];
    #pragma unroll
    for (int j = 0; j < 48; j++) wr[j] = w[tid * 48 + j];
    float bv = bias[tid];
    __syncthreads();

    int rb = rowbase + (b * Hout + y) * Wout;
    for (int x = 0; x < Wout; x++) {
        float acc = 0.f;
        #pragma unroll
        for (int ci = 0; ci < 3; ci++)
            #pragma unroll
            for (int kh = 0; kh < 4; kh++) {
                const float* pr = &patch[(ci * 4 + kh) * Wimg + 4 * x];
                #pragma unroll
                for (int kw = 0; kw < 4; kw++)
                    acc = fmaf(pr[kw], wr[ci * 16 + kh * 4 + kw], acc);
            }
        feat[(size_t)(rb + x) * 256 + tid] = acc + bv;
    }
}

// ---- bulk MFMA match. Block: 128 virtual-rows x 128 codes; grid 592x4.
__launch_bounds__(256, 3)
__global__ void match_bulk(const float* __restrict__ feat,
                           const unsigned short* __restrict__ cbs,
                           const float* __restrict__ cnf,
                           float* __restrict__ partials) {
    __shared__ unsigned short A0[128][40], A1[128][40], B0s[128][40], B1s[128][40];
    int bid = blockIdx.x;
    int codeblk = bid & 3, rowtile = bid >> 2;     // 4 x 592
    int book = (rowtile >= 336) ? 1 : 0;
    int frow0 = book ? (rowtile - 336) * 128 : rowtile * 128;
    int vr0 = rowtile * 128;
    int tid = threadIdx.x;
    int wid = tid >> 6, l = tid & 63;
    int waveY = wid & 1, waveX = wid >> 1;
    int lm = l & 15, lq = l >> 4, kq = lq * 8;

    f32x4 acc[4][4];
    #pragma unroll
    for (int rt = 0; rt < 4; rt++)
        #pragma unroll
        for (int ct = 0; ct < 4; ct++) acc[rt][ct] = (f32x4)0.0f;

    const float4* feat4 = (const float4*)feat;
    const unsigned short* cbbase = cbs + (size_t)book * 262144;

    for (int kc = 0; kc < 8; kc++) {
        #pragma unroll
        for (int i = 0; i < 4; i++) {
            int f4 = i * 256 + tid;
            int row = f4 >> 3, c4 = f4 & 7;
            float4 v = feat4[(size_t)(frow0 + row) * 64 + kc * 8 + c4];
            ushort4 h0, h1;
            h0.x = f2bf(v.x); h1.x = f2bf(v.x - bf2f(h0.x));
            h0.y = f2bf(v.y); h1.y = f2bf(v.y - bf2f(h0.y));
            h0.z = f2bf(v.z); h1.z = f2bf(v.z - bf2f(h0.z));
            h0.w = f2bf(v.w); h1.w = f2bf(v.w - bf2f(h0.w));
            *(ushort4*)&A0[row][c4 * 4] = h0;
            *(ushort4*)&A1[row][c4 * 4] = h1;
        }
        #pragma unroll
        for (int i = 0; i < 4; i++) {
            int lid = i * 256 + tid;
            int split = lid >> 9, rem = lid & 511;
            int code = rem >> 2, c8 = (rem & 3) * 8;
            uint4 raw = *(const uint4*)(cbbase + ((size_t)split * 512 + codeblk * 128 + code) * 256
                                        + kc * 32 + c8);
            if (split) *(uint4*)&B1s[code][c8] = raw;
            else       *(uint4*)&B0s[code][c8] = raw;
        }
        __syncthreads();
        short8 a0[4], a1[4], b0[4], b1[4];
        #pragma unroll
        for (int t = 0; t < 4; t++) {
            a0[t] = *(const short8*)&A0[waveY * 64 + t * 16 + lm][kq];
            a1[t] = *(const short8*)&A1[waveY * 64 + t * 16 + lm][kq];
            b0[t] = *(const short8*)&B0s[waveX * 64 + t * 16 + lm][kq];
            b1[t] = *(const short8*)&B1s[waveX * 64 + t * 16 + lm][kq];
        }
        #pragma unroll
        for (int rt = 0; rt < 4; rt++)
            #pragma unroll
            for (int ct = 0; ct < 4; ct++) {
                acc[rt][ct] = __builtin_amdgcn_mfma_f32_16x16x32_bf16(a0[rt], b0[ct], acc[rt][ct], 0, 0, 0);
                acc[rt][ct] = __builtin_amdgcn_mfma_f32_16x16x32_bf16(a0[rt], b1[ct], acc[rt][ct], 0, 0, 0);
                acc[rt][ct] = __builtin_amdgcn_mfma_f32_16x16x32_bf16(a1[rt], b0[ct], acc[rt][ct], 0, 0, 0);
            }
        __syncthreads();
    }

    float cnv[4];
    #pragma unroll
    for (int ct = 0; ct < 4; ct++)
        cnv[ct] = cnf[book * 512 + codeblk * 128 + waveX * 64 + ct * 16 + lm];
    float4* part4 = (float4*)partials;

    #pragma unroll
    for (int rt = 0; rt < 4; rt++) {
        #pragma unroll
        for (int j = 0; j < 4; j++) {
            float v[4];
            #pragma unroll
            for (int ct = 0; ct < 4; ct++)
                v[ct] = 2.0f * acc[rt][ct][j] - cnv[ct];
            float m1 = v[0], m2 = -3.4e38f;
            int k1 = codeblk * 128 + waveX * 64 + 0 * 16 + lm;
            #pragma unroll
            for (int ct = 1; ct < 4; ct++) {
                int kk = codeblk * 128 + waveX * 64 + ct * 16 + lm;
                if (v[ct] > m1 || (v[ct] == m1 && kk < k1)) { m2 = m1; m1 = v[ct]; k1 = kk; }
                else m2 = fmaxf(m2, v[ct]);
            }
            #pragma unroll
            for (int off = 1; off < 16; off <<= 1) {
                float mo1 = __shfl_xor(m1, off);
                float mo2 = __shfl_xor(m2, off);
                int ko1 = __shfl_xor(k1, off);
                if (mo1 > m1 || (mo1 == m1 && ko1 < k1)) { m2 = fmaxf(m1, mo2); m1 = mo1; k1 = ko1; }
                else m2 = fmaxf(m2, mo1);
            }
            float s = 0.f;
            #pragma unroll
            for (int ct = 0; ct < 4; ct++) s += expf(v[ct] - m1);
            #pragma unroll
            for (int off = 1; off < 16; off <<= 1) s += __shfl_xor(s, off);
            if (lm == 0) {
                int vr = vr0 + waveY * 64 + rt * 16 + lq * 4 + j;
                float4 st = make_float4(m1, m2, __int_as_float(k1), s);
                part4[(size_t)vr * 8 + codeblk * 2 + waveX] = st;
            }
        }
    }
}

// ---- combine the 8 per-slice partials of each row; write idx/prob; flag rescues
__global__ void combine_rows(const float* __restrict__ partials,
                             int* __restrict__ idx1, int* __restrict__ idx2,
                             float* __restrict__ prob,
                             int* __restrict__ rlist, int* __restrict__ cnt) {
    int vr = blockIdx.x * 256 + threadIdx.x;      // grid 296*256 = 75776 exact
    const float4* p = (const float4*)partials + (size_t)vr * 8;
    float sm[8], ss[8];
    float4 a = p[0];
    float m1 = a.x, m2 = a.y; int k1 = __float_as_int(a.z);
    sm[0] = a.x; ss[0] = a.w;
    #pragma unroll
    for (int j = 1; j < 8; j++) {
        float4 b = p[j];
        sm[j] = b.x; ss[j] = b.w;
        int kk = __float_as_int(b.z);
        if (b.x > m1 || (b.x == m1 && kk < k1)) { m2 = fmaxf(m1, b.y); m1 = b.x; k1 = kk; }
        else m2 = fmaxf(m2, b.x);
    }
    float S = 0.f;
    #pragma unroll
    for (int j = 0; j < 8; j++) S += ss[j] * expf(sm[j] - m1);
    if (vr < 43008) { idx1[vr] = k1; prob[vr] = 1.0f / S; }
    else idx2[vr - 43008] = k1;
    if (m1 - m2 < EPS_V) { int pos = atomicAdd(cnt, 1); rlist[pos] = vr; }
}

// ---- exact fp64 recompute for flagged rows (idx + prob)
__launch_bounds__(256)
__global__ void rescue_exact(const float* __restrict__ feat,
                             const float* __restrict__ codebooks,
                             const double* __restrict__ cnd,
                             const int* __restrict__ rlist, const int* __restrict__ cnt,
                             int* __restrict__ idx1, int* __restrict__ idx2,
                             float* __restrict__ prob) {
    __shared__ double sfd[256];
    __shared__ double rv[4]; __shared__ int rk[4]; __shared__ double rs[4];
    __shared__ double gvmax; __shared__ int gkmax;
    int tid = threadIdx.x;
    int lane = tid & 63, wave = tid >> 6;
    int n = cnt[0];
    for (int e = blockIdx.x; e < n; e += gridDim.x) {
        int vr = rlist[e];
        int book = vr >= 43008;
        int fr = book ? vr - 43008 : vr;
        sfd[tid] = (double)feat[(size_t)fr * 256 + tid];
        __syncthreads();
        const float* cb = codebooks + (size_t)book * 131072;
        double vloc[2]; int kk[2];
        #pragma unroll
        for (int h = 0; h < 2; h++) {
            int k = h * 256 + tid;
            const float* cp = cb + (size_t)k * 256;
            double dot = 0.0;
            for (int c = 0; c < 256; c++) dot = fma((double)cp[c], sfd[c], dot);
            vloc[h] = 2.0 * dot - cnd[book * 512 + k];
            kk[h] = k;
        }
        double bv = vloc[0]; int bk = kk[0];
        if (vloc[1] > bv || (vloc[1] == bv && kk[1] < bk)) { bv = vloc[1]; bk = kk[1]; }
        #pragma unroll
        for (int off = 32; off; off >>= 1) {
            double vo = __shfl_xor(bv, off);
            int ko = __shfl_xor(bk, off);
            if (vo > bv || (vo == bv && ko < bk)) { bv = vo; bk = ko; }
        }
        if (lane == 0) { rv[wave] = bv; rk[wave] = bk; }
        __syncthreads();
        if (tid == 0) {
            double v0 = rv[0]; int K = rk[0];
            #pragma unroll
            for (int w = 1; w < 4; w++)
                if (rv[w] > v0 || (rv[w] == v0 && rk[w] < K)) { v0 = rv[w]; K = rk[w]; }
            gvmax = v0; gkmax = K;
        }
        __syncthreads();
        double vm = gvmax;
        double s = exp(vloc[0] - vm) + exp(vloc[1] - vm);
        #pragma unroll
        for (int off = 32; off; off >>= 1) s += __shfl_xor(s, off);
        if (lane == 0) rs[wave] = s;
        __syncthreads();
        if (tid == 0) {
            double S = ((rs[0] + rs[1]) + rs[2]) + rs[3];
            if (book) idx2[fr] = gkmax;
            else { idx1[vr] = gkmax; prob[vr] = (float)(1.0 / S); }
        }
        __syncthreads();
    }
}

// ---- fuse stage 1: decide per pixel; defer prob-fragile pixels to fuse2
__launch_bounds__(256)
__global__ void fuse1(const float* __restrict__ feat,
                      const float* __restrict__ prob,
                      const int* __restrict__ idx1, const int* __restrict__ idx2,
                      const float* __restrict__ codebooks,
                      float* __restrict__ out0, float* __restrict__ outZ,
                      float* __restrict__ outS,
                      int* __restrict__ dlist, int* __restrict__ cnt) {
    __shared__ int rsel_s[64], i1_s[64], i2_s[64], defer_s[64];
    int tid = threadIdx.x;
    int b = blockIdx.x >> 6, y = blockIdx.x & 63;

    if (tid < 64) {
        int x = tid;
        int r0 = (b * 64 + y) * 64 + x;
        int r1 = 32768 + (b * 32 + (y >> 1)) * 32 + (x >> 1);
        int r2 = 40960 + (b * 16 + (y >> 2)) * 16 + (x >> 2);
        float p0 = prob[r0], p1 = prob[r1], p2 = prob[r2];
        int rsel = r0; float best = p0;          // strict > keeps first-max
        if (p1 > best) { best = p1; rsel = r1; }
        if (p2 > best) { best = p2; rsel = r2; }
        float second = (rsel == r0) ? fmaxf(p1, p2)
                     : (rsel == r1) ? fmaxf(p0, p2) : fmaxf(p0, p1);
        int defer = (best - second < EPS_P_REL * best) ? 1 : 0;
        defer_s[x] = defer;
        if (defer) {
            int pos = atomicAdd(cnt + 1, 1);
            dlist[pos] = (b << 12) | (y << 6) | x;
            rsel_s[x] = r0; i1_s[x] = 0; i2_s[x] = 0;   // unused
        } else {
            int i1 = idx1[rsel], i2 = idx2[r0];
            rsel_s[x] = rsel; i1_s[x] = i1; i2_s[x] = i2;
            size_t zb = (size_t)b * 8192 + (size_t)y * 64 + x;
            outZ[zb] = (float)i1;
            outZ[zb + 4096] = (float)i2;
        }
    }
    __syncthreads();

    int x = tid & 63, cc = tid >> 6;
    int r0 = (b * 64 + y) * 64 + x;
    const float* e0p = feat + (size_t)r0 * 256;
    const float* e1p = feat + (size_t)rsel_s[x] * 256;
    const float* q1p = codebooks + (size_t)i1_s[x] * 256;
    const float* q2p = codebooks + (size_t)(512 + i2_s[x]) * 256;
    int defer = defer_s[x];
    for (int it = 0; it < 64; it++) {
        int c = it * 4 + cc;
        float e0 = e0p[c];
        size_t o = (((size_t)b * 256 + c) * 64 + y) * 64 + x;
        out0[o] = e0;                              // out0 never depends on decisions
        if (!defer) {
            float e1 = e1p[c], q1 = q1p[c], q2 = q2p[c];
            float ef = (e1 + e0) * 0.5f;
            float qf = (q1 + q2) * 0.5f;
            outS[o] = ef + (qf - ef);
        }
    }
}

// ---- fuse stage 2: deferred pixels, full fp64 (3 rows x 512 codes each)
__launch_bounds__(256)
__global__ void fuse2(const float* __restrict__ feat,
                      const float* __restrict__ codebooks,
                      const double* __restrict__ cnd,
                      const int* __restrict__ idx2,
                      const int* __restrict__ dlist, const int* __restrict__ cnt,
                      float* __restrict__ outZ, float* __restrict__ outS) {
    __shared__ double sfd[256];
    __shared__ double rv[4]; __shared__ int rk[4]; __shared__ double rs[4];
    __shared__ double gvmax;
    __shared__ double pRes[3]; __shared__ int kRes[3];
    __shared__ int selS, i2S;
    int tid = threadIdx.x;
    int lane = tid & 63, wave = tid >> 6;
    int n = cnt[1];
    for (int e = blockIdx.x; e < n; e += gridDim.x) {
        int px = dlist[e];
        int b = px >> 12, y = (px >> 6) & 63, x = px & 63;
        int r0 = (b * 64 + y) * 64 + x;
        int r1 = 32768 + (b * 32 + (y >> 1)) * 32 + (x >> 1);
        int r2 = 40960 + (b * 16 + (y >> 2)) * 16 + (x >> 2);
        int rows[3] = {r0, r1, r2};
        for (int s3 = 0; s3 < 3; s3++) {
            sfd[tid] = (double)feat[(size_t)rows[s3] * 256 + tid];
            __syncthreads();
            double vloc[2];
            #pragma unroll
            for (int h = 0; h < 2; h++) {
                int k = h * 256 + tid;
                const float* cp = codebooks + (size_t)k * 256;
                double dot = 0.0;
                for (int c = 0; c < 256; c++) dot = fma((double)cp[c], sfd[c], dot);
                vloc[h] = 2.0 * dot - cnd[k];
            }
            double bv = vloc[0]; int bk = tid;
            if (vloc[1] > bv) { bv = vloc[1]; bk = tid + 256; }
            #pragma unroll
            for (int off = 32; off; off >>= 1) {
                double vo = __shfl_xor(bv, off);
                int ko = __shfl_xor(bk, off);
                if (vo > bv || (vo == bv && ko < bk)) { bv = vo; bk = ko; }
            }
            if (lane == 0) { rv[wave] = bv; rk[wave] = bk; }
            __syncthreads();
            if (tid == 0) {
                double v0 = rv[0]; int K = rk[0];
                #pragma unroll
                for (int w = 1; w < 4; w++)
                    if (rv[w] > v0 || (rv[w] == v0 && rk[w] < K)) { v0 = rv[w]; K = rk[w]; }
                gvmax = v0; kRes[s3] = K;
            }
            __syncthreads();
            double vm = gvmax;
            double s = exp(vloc[0] - vm) + exp(vloc[1] - vm);
            #pragma unroll
            for (int off = 32; off; off >>= 1) s += __shfl_xor(s, off);
            if (lane == 0) rs[wave] = s;
            __syncthreads();
            if (tid == 0) pRes[s3] = 1.0 / (((rs[0] + rs[1]) + rs[2]) + rs[3]);
            __syncthreads();
        }
        if (tid == 0) {
            int sel = 0; double best = pRes[0];
            if (pRes[1] > best) { best = pRes[1]; sel = 1; }
            if (pRes[2] > best) { best = pRes[2]; sel = 2; }
            selS = sel;
            int i2 = idx2[r0];
            i2S = i2;
            size_t zb = (size_t)b * 8192 + (size_t)y * 64 + x;
            outZ[zb] = (float)kRes[sel];
            outZ[zb + 4096] = (float)i2;
        }
        __syncthreads();
        int sel = selS;
        int c = tid;
        float e0 = feat[(size_t)r0 * 256 + c];
        float e1 = feat[(size_t)rows[sel] * 256 + c];
        float q1 = codebooks[(size_t)kRes[sel] * 256 + c];
        float q2 = codebooks[(size_t)(512 + i2S) * 256 + c];
        float ef = (e1 + e0) * 0.5f;
        float qf = (q1 + q2) * 0.5f;
        size_t o = (((size_t)b * 256 + c) * 64 + y) * 64 + x;
        outS[o] = ef + (qf - ef);
        __syncthreads();
    }
}

extern "C" void kernel_launch(void* const* d_in, const int* in_sizes, int n_in,
                              void* d_out, int out_size, void* d_ws, size_t ws_size,
                              hipStream_t stream) {
    (void)in_sizes; (void)n_in; (void)out_size; (void)ws_size;
    const float* image     = (const float*)d_in[0];   // [8,3,256,256]
    const float* conv_w    = (const float*)d_in[1];   // [256,3,4,4]
    const float* conv_b    = (const float*)d_in[2];   // [256]
    const float* codebooks = (const float*)d_in[3];   // [4,512,256]

    float*  ws    = (float*)d_ws;
    float*  feat  = ws + FEAT_OFF;
    float*  parts = ws + PART_OFF;
    float*  prob  = ws + PROB_OFF;
    int*    idx1  = (int*)(ws + IDX1_OFF);
    int*    idx2  = (int*)(ws + IDX2_OFF);
    float*  cnf   = ws + CNF_OFF;
    double* cnd   = (double*)(ws + CND_OFF);
    unsigned short* cbs = (unsigned short*)(ws + CBS_OFF);
    float*  img1  = ws + IMG1_OFF;
    float*  img2  = ws + IMG2_OFF;
    int*    rlist = (int*)(ws + RLIST_OFF);
    int*    dlist = (int*)(ws + DLIST_OFF);
    int*    cnt   = (int*)(ws + CNT_OFF);

    float* out  = (float*)d_out;
    float* out0 = out;
    float* outZ = out + 8388608;
    float* outS = out + 8454144;

    zero_cnt<<<1, 64, 0, stream>>>(cnt);
    ds_kernel<<<1536, 256, 0, stream>>>(image, img1, 128, 128, 0, 2);
    ds_kernel<<<384, 256, 0, stream>>>(image, img2, 64, 64, 1, 4);
    cnorm_kernel<<<1024, 64, 0, stream>>>(codebooks, cnd, cnf);
    split_cb<<<1024, 256, 0, stream>>>(codebooks, cbs);
    encode_all<<<896, 256, 0, stream>>>(image, img1, img2, conv_w, conv_b, feat);
    match_bulk<<<2368, 256, 0, stream>>>(feat, cbs, cnf, parts);
    combine_rows<<<296, 256, 0, stream>>>(parts, idx1, idx2, prob, rlist, cnt);
    rescue_exact<<<1024, 256, 0, stream>>>(feat, codebooks, cnd, rlist, cnt, idx1, idx2, prob);
    fuse1<<<512, 256, 0, stream>>>(feat, prob, idx1, idx2, codebooks, out0, outZ, outS, dlist, cnt);
    fuse2<<<512, 256, 0, stream>>>(feat, codebooks, cnd, idx2, dlist, cnt, outZ, outS);
}